// Round 1
// 1141.773 us; speedup vs baseline: 1.1374x; 1.1374x over previous
//
#include <hip/hip_runtime.h>
#include <hip/hip_bf16.h>
#include <math.h>

#define H 2048
#define V 32000
#define T 512
#define TOK 2048        // B*T tokens per model
#define IGN (-100)

// round-1 fallback tile
#define BM 64
#define BN 64
#define BK 32
#define NCH (V / BN)    // 500 chunks of 64 cols (shared by both paths)

typedef unsigned short u16;
typedef __attribute__((ext_vector_type(8))) short short8;
typedef __attribute__((ext_vector_type(4))) float f32x4;

__device__ __forceinline__ u16 f2bf(float f) {
    unsigned int u = __float_as_uint(f);
    u += 0x7fffu + ((u >> 16) & 1u);   // round-to-nearest-even
    return (u16)(u >> 16);
}

#define GLD16(gp, lp) __builtin_amdgcn_global_load_lds( \
    (const __attribute__((address_space(1))) unsigned int*)(gp), \
    (__attribute__((address_space(3))) unsigned int*)(lp), 16, 0, 0)

// ---------------------------------------------------------------------------
// Convert f32 -> bf16 (RNE), vectorized. n4 = element count / 4.
// ---------------------------------------------------------------------------
__global__ __launch_bounds__(256) void f32_to_bf16(
    const float* __restrict__ src, u16* __restrict__ dst, int n4)
{
    for (int i = blockIdx.x * 256 + threadIdx.x; i < n4; i += gridDim.x * 256) {
        float4 v = ((const float4*)src)[i];
        ushort4 o;
        o.x = f2bf(v.x); o.y = f2bf(v.y); o.z = f2bf(v.z); o.w = f2bf(v.w);
        ((ushort4*)dst)[i] = o;
    }
}

// ---------------------------------------------------------------------------
// 256x256 tile, BK=64, 8 waves (2M x 4N), 8-phase counted-vmcnt schedule
// (T2 XOR-swizzle + T3/T4 8-phase counted vmcnt + T5 setprio + T1 XCD swz).
// Per wave: 128x64 output, acc[8][4] f32x4. LDS 128 KiB = 2 buf x (A+B).
// Deterministic stage placement: a half-tile is staged only in a phase
// strictly AFTER the barrier that retires its region's last ds_reads.
//   reads:  P1: A[mh0]+B(all) of buf0   P3: A[mh1] of buf0
//           P5: A[mh0]+B(all) of buf1   P7: A[mh1] of buf1
//   stages: P1: (u+1).A1->buf1  P2: (u+2).B0->buf0  P3: (u+2).B1->buf0
//           P4: (u+2).A0->buf0  P5: (u+2).A1->buf0  P6: (u+3).B0->buf1
//           P7: (u+3).B1->buf1  P8: (u+3).A0->buf1
//   vmcnt(6) at P4 (tile u+1 fully landed before P5 reads) and P8 (tile
//   u+2 landed before next P1). 3 half-tiles (6 loads) in flight.
// Fused epilogue: per-row (max, sumexp) partials over the wave's 64 cols.
// ---------------------------------------------------------------------------
__global__ __launch_bounds__(512, 2) void gemm_bf16(
    const u16* __restrict__ Xb, const u16* __restrict__ Wb,
    float* __restrict__ ms_m, float* __restrict__ ms_s)
{
    __shared__ __align__(16) u16 lds[65536];   // 128 KiB
    // layout (shorts): buf0 A:[0,16384) B:[16384,32768) ; buf1 A:[32768,49152) B:[49152,65536)
    // each A/B = 2 halves of 128 rows x 64 k ; half = 8192 shorts

    const int tid  = threadIdx.x;
    const int wave = tid >> 6;
    const int lane = tid & 63;
    const int q    = lane >> 4;
    const int rl   = lane & 15;
    const int wm   = wave >> 2;      // 0..1  (M half)
    const int wn   = wave & 3;       // 0..3  (N quarter)

    // XCD-chunked bijective swizzle: 2000 wgs, 2000 % 8 == 0.
    const int lin = (int)blockIdx.x;
    const int wg  = (lin & 7) * 250 + (lin >> 3);
    const int bx  = wg & 7;          // 8 token tiles
    const int rem = wg >> 3;         // 0..249
    const int by  = rem % 125;       // 125 vocab tiles
    const int model = rem / 125;

    const size_t tokBase = (size_t)bx * 256;
    const size_t vBase   = (size_t)by * 256;

    const u16* __restrict__ A  = Xb + (size_t)model * (2048ULL * H) + tokBase * H;
    const u16* __restrict__ Bm = Wb + (size_t)model * ((size_t)V * H) + vBase * H;
    const u16* __restrict__ A1p = A  + 128 * H;
    const u16* __restrict__ B1p = Bm + 128 * H;

    // Staging: half-tile = 128 rows x 64 k = 1024 16B-slots; 2 GLD16 insts x
    // 512 thr x 16B. Linear LDS dest (gld_lds requirement); XOR swizzle
    // (phys slot s holds logical s ^ (r&7)) realized on the GLOBAL address.
    const int G0 = wave * 64 + lane;
    const int G1 = G0 + 512;
    const int r0 = G0 >> 3, s0 = (G0 & 7) ^ (r0 & 7);
    const int r1 = G1 >> 3, s1 = (G1 & 7) ^ (r1 & 7);
    const int off0 = r0 * H + s0 * 8;
    const int off1 = r1 * H + s1 * 8;
    const int ldsS0 = wave * 512;           // shorts within half-buffer
    const int ldsS1 = 4096 + wave * 512;

#define STAGE(gp, hb) do { \
    GLD16((gp) + off0, lds + (hb) + ldsS0); \
    GLD16((gp) + off1, lds + (hb) + ldsS1); \
} while (0)

    // Fragment LDS offsets within a half-buffer (shorts). Read logical slot
    // (ks*4+q) at row r -> phys slot ^(r&7); ks=1 is ^32 shorts (bit flip).
    const int sB = (q ^ (rl & 7)) << 3;
    int aoff[8], boff[4];
#pragma unroll
    for (int im = 0; im < 8; ++im) aoff[im] = (im * 16 + rl) * 64 + sB;
#pragma unroll
    for (int in = 0; in < 4; ++in) boff[in] = ((wn & 1) * 64 + in * 16 + rl) * 64 + sB;

    const int aB0 = wm * 8192;                    // buf0 A, this wave's half
    const int aB1 = 32768 + wm * 8192;            // buf1 A
    const int bB0 = 16384 + (wn >> 1) * 8192;     // buf0 B, this wave's half
    const int bB1 = 49152 + (wn >> 1) * 8192;     // buf1 B

    short8 af[4][2], bf[4][2];
    f32x4 acc[8][4];
#pragma unroll
    for (int a = 0; a < 8; ++a)
#pragma unroll
        for (int b = 0; b < 4; ++b) acc[a][b] = (f32x4){0.f, 0.f, 0.f, 0.f};

#define LDA(cb, mh) do { \
    _Pragma("unroll") \
    for (int f = 0; f < 4; ++f) { \
        const int o_ = (cb) + aoff[(mh) * 4 + f]; \
        af[f][0] = *(const short8*)(lds + o_); \
        af[f][1] = *(const short8*)(lds + (o_ ^ 32)); \
    } } while (0)

#define LDB(cb) do { \
    _Pragma("unroll") \
    for (int f = 0; f < 4; ++f) { \
        const int o_ = (cb) + boff[f]; \
        bf[f][0] = *(const short8*)(lds + o_); \
        bf[f][1] = *(const short8*)(lds + (o_ ^ 32)); \
    } } while (0)

#define QUAD(mh, nh) do { \
    _Pragma("unroll") \
    for (int f = 0; f < 4; ++f) \
    _Pragma("unroll") \
    for (int g = 0; g < 2; ++g) { \
        acc[(mh)*4+f][(nh)*2+g] = __builtin_amdgcn_mfma_f32_16x16x32_bf16( \
            af[f][0], bf[(nh)*2+g][0], acc[(mh)*4+f][(nh)*2+g], 0, 0, 0); \
        acc[(mh)*4+f][(nh)*2+g] = __builtin_amdgcn_mfma_f32_16x16x32_bf16( \
            af[f][1], bf[(nh)*2+g][1], acc[(mh)*4+f][(nh)*2+g], 0, 0, 0); \
    } } while (0)

#define SYNC_PRE() do { \
    __builtin_amdgcn_s_barrier(); \
    asm volatile("s_waitcnt lgkmcnt(0)" ::: "memory"); \
    __builtin_amdgcn_s_setprio(1); \
} while (0)

#define SYNC_POST() do { \
    __builtin_amdgcn_s_setprio(0); \
    __builtin_amdgcn_s_barrier(); \
    asm volatile("" ::: "memory"); \
} while (0)

    // prologue: t0 {B0,B1,A0,A1} -> buf0 ; t1 {B0,B1,A0} -> buf1 (7 half-tiles)
    STAGE(Bm,        16384); STAGE(B1p,       24576);
    STAGE(A,             0); STAGE(A1p,        8192);
    STAGE(Bm + 64,   49152); STAGE(B1p + 64,  57344);
    STAGE(A + 64,    32768);
    asm volatile("s_waitcnt vmcnt(6)" ::: "memory");   // 14 issued -> t0's 8 landed
    __builtin_amdgcn_s_barrier();
    asm volatile("" ::: "memory");

#pragma unroll 1
    for (int i = 0; i < 15; ++i) {          // tiles u=2i (buf0), u+1 (buf1)
        const int k1 = i * 128 + 64, k2 = k1 + 64, k3 = k2 + 64;
        // P1
        LDA(aB0, 0); LDB(bB0);
        STAGE(A1p + k1, 40960);             // (u+1).A1 -> buf1
        SYNC_PRE(); QUAD(0, 0); SYNC_POST();
        // P2
        STAGE(Bm + k2, 16384);              // (u+2).B0 -> buf0
        SYNC_PRE(); QUAD(0, 1); SYNC_POST();
        // P3
        LDA(aB0, 1);
        STAGE(B1p + k2, 24576);             // (u+2).B1 -> buf0
        SYNC_PRE(); QUAD(1, 1); SYNC_POST();
        // P4
        STAGE(A + k2, 0);                   // (u+2).A0 -> buf0
        asm volatile("s_waitcnt vmcnt(6)" ::: "memory");
        SYNC_PRE(); QUAD(1, 0); SYNC_POST();
        // P5
        LDA(aB1, 0); LDB(bB1);
        STAGE(A1p + k2, 8192);              // (u+2).A1 -> buf0
        SYNC_PRE(); QUAD(0, 0); SYNC_POST();
        // P6
        STAGE(Bm + k3, 49152);              // (u+3).B0 -> buf1
        SYNC_PRE(); QUAD(0, 1); SYNC_POST();
        // P7
        LDA(aB1, 1);
        STAGE(B1p + k3, 57344);             // (u+3).B1 -> buf1
        SYNC_PRE(); QUAD(1, 1); SYNC_POST();
        // P8
        STAGE(A + k3, 32768);               // (u+3).A0 -> buf1
        asm volatile("s_waitcnt vmcnt(6)" ::: "memory");
        SYNC_PRE(); QUAD(1, 0); SYNC_POST();
    }

    // tail: tiles 30 (buf0), 31 (buf1). Stage t31.A1, drain, compute barrier-free.
    STAGE(A1p + 31 * 64, 40960);
    asm volatile("s_waitcnt vmcnt(0)" ::: "memory");
    __builtin_amdgcn_s_barrier();
    asm volatile("" ::: "memory");

    LDA(aB0, 0); LDB(bB0); QUAD(0, 0); QUAD(0, 1);
    LDA(aB0, 1);           QUAD(1, 0); QUAD(1, 1);
    LDA(aB1, 0); LDB(bB1); QUAD(0, 0); QUAD(0, 1);
    LDA(aB1, 1);           QUAD(1, 0); QUAD(1, 1);

    // Epilogue: per-row partial (max, sumexp) over this wave's 64 cols.
    // C layout: row = wm*128 + im*16 + q*4 + i, col = wn*64 + in*16 + rl.
    const int chunk = by * 4 + wn;                       // global col / 64
    const size_t rowB = (size_t)model * TOK + tokBase + (size_t)wm * 128;
#pragma unroll
    for (int im = 0; im < 8; ++im) {
#pragma unroll
        for (int i2 = 0; i2 < 4; ++i2) {
            float v0 = acc[im][0][i2], v1 = acc[im][1][i2];
            float v2 = acc[im][2][i2], v3 = acc[im][3][i2];
            float mx = fmaxf(fmaxf(v0, v1), fmaxf(v2, v3));
#pragma unroll
            for (int off = 1; off < 16; off <<= 1)
                mx = fmaxf(mx, __shfl_xor(mx, off));
            float s = __expf(v0 - mx) + __expf(v1 - mx)
                    + __expf(v2 - mx) + __expf(v3 - mx);
#pragma unroll
            for (int off = 1; off < 16; off <<= 1)
                s += __shfl_xor(s, off);
            if (rl == 0) {
                size_t idx = (rowB + im * 16 + q * 4 + i2) * NCH + chunk;
                ms_m[idx] = mx;
                ms_s[idx] = s;
            }
        }
    }
#undef STAGE
#undef LDA
#undef LDB
#undef QUAD
#undef SYNC_PRE
#undef SYNC_POST
}

// ---------------------------------------------------------------------------
// Round-1 fallback GEMM (known correct) — used only if ws too small.
// ---------------------------------------------------------------------------
__global__ __launch_bounds__(256) void gemm_partial(
    const float* __restrict__ X,  const float* __restrict__ Xr,
    const float* __restrict__ Wp, const float* __restrict__ Wr,
    float* __restrict__ ms_m, float* __restrict__ ms_s)
{
    __shared__ float smemF[64 * 65];
    short* smemS = (short*)smemF;
    short* ldsA = smemS;
    short* ldsB = smemS + 64 * 40;

    const int tid     = threadIdx.x;
    const int model   = blockIdx.z;
    const int tokBase = blockIdx.x * BM;
    const int vBase   = blockIdx.y * BN;

    const float* __restrict__ Xp = model ? Xr : X;
    const float* __restrict__ Wm = model ? Wr : Wp;

    const int lane = tid & 63;
    const int wave = tid >> 6;
    const int q    = lane >> 4;
    const int rl   = lane & 15;
    const int m0   = (wave >> 1) * 32;
    const int n0   = (wave & 1) * 32;

    f32x4 acc[2][2];
    for (int a = 0; a < 2; a++)
        for (int b = 0; b < 2; b++)
            acc[a][b] = (f32x4){0.f, 0.f, 0.f, 0.f};

    for (int kk = 0; kk < H / BK; kk++) {
        const int k0 = kk * BK;
        __syncthreads();
        for (int rep = 0; rep < 2; rep++) {
            int i   = tid + rep * 256;
            int row = i >> 3;
            int cf  = (i & 7) * 4;
            const float4 va = *(const float4*)(Xp + (size_t)(tokBase + row) * H + k0 + cf);
            short* pa = ldsA + row * 40 + cf;
            pa[0] = (short)f2bf(va.x); pa[1] = (short)f2bf(va.y);
            pa[2] = (short)f2bf(va.z); pa[3] = (short)f2bf(va.w);
            const float4 vb = *(const float4*)(Wm + (size_t)(vBase + row) * H + k0 + cf);
            short* pb = ldsB + row * 40 + cf;
            pb[0] = (short)f2bf(vb.x); pb[1] = (short)f2bf(vb.y);
            pb[2] = (short)f2bf(vb.z); pb[3] = (short)f2bf(vb.w);
        }
        __syncthreads();

        short8 aF[2], bF[2];
        for (int im = 0; im < 2; im++)
            aF[im] = *(const short8*)(ldsA + (m0 + im * 16 + rl) * 40 + q * 8);
        for (int in = 0; in < 2; in++)
            bF[in] = *(const short8*)(ldsB + (n0 + in * 16 + rl) * 40 + q * 8);

        for (int im = 0; im < 2; im++)
            for (int in = 0; in < 2; in++)
                acc[im][in] = __builtin_amdgcn_mfma_f32_16x16x32_bf16(
                    aF[im], bF[in], acc[im][in], 0, 0, 0);
    }

    __syncthreads();
    for (int im = 0; im < 2; im++)
        for (int in = 0; in < 2; in++)
            for (int i = 0; i < 4; i++)
                smemF[(m0 + im * 16 + q * 4 + i) * 65 + (n0 + in * 16 + rl)] =
                    acc[im][in][i];
    __syncthreads();

    if (tid < 64) {
        const float* rowp = smemF + tid * 65;
        float m = -INFINITY;
        for (int j = 0; j < 64; j++) m = fmaxf(m, rowp[j]);
        float s = 0.f;
        for (int j = 0; j < 64; j++) s += __expf(rowp[j] - m);
        size_t idx = ((size_t)model * TOK + (tokBase + tid)) * NCH + blockIdx.y;
        ms_m[idx] = m;
        ms_s[idx] = s;
    }
}

// ---------------------------------------------------------------------------
// Label logit per (model, token). One wave per token.
// ---------------------------------------------------------------------------
__global__ __launch_bounds__(256) void label_logit(
    const float* __restrict__ X,  const float* __restrict__ Xr,
    const float* __restrict__ Wp, const float* __restrict__ Wr,
    const int* __restrict__ y, float* __restrict__ z)
{
    int id    = blockIdx.x * 4 + (threadIdx.x >> 6);  // 0..4095
    int lane  = threadIdx.x & 63;
    int model = id >> 11;
    int token = id & 2047;
    const float* __restrict__ Xp = model ? Xr : X;
    const float* __restrict__ Wm = model ? Wr : Wp;
    int lab = y[token];
    float sum = 0.f;
    if (lab != IGN) {
        const float* xp = Xp + (size_t)token * H;
        const float* wp = Wm + (size_t)lab * H;
        for (int c = lane; c < H; c += 64) sum += xp[c] * wp[c];
    }
    for (int off = 32; off; off >>= 1) sum += __shfl_down(sum, off);
    if (lane == 0) z[id] = sum;
}

// ---------------------------------------------------------------------------
// Combine 500 partial (m,s) per (model,token) -> logp.
// ---------------------------------------------------------------------------
__global__ __launch_bounds__(256) void lse_logp(
    const float* __restrict__ ms_m, const float* __restrict__ ms_s,
    const float* __restrict__ z, float* __restrict__ logp)
{
    int id = blockIdx.x;   // 0..4095
    int t  = threadIdx.x;
    __shared__ float red[256];
    const float* mrow = ms_m + (size_t)id * NCH;
    const float* srow = ms_s + (size_t)id * NCH;

    float m = -INFINITY;
    for (int c = t; c < NCH; c += 256) m = fmaxf(m, mrow[c]);
    red[t] = m; __syncthreads();
    for (int w = 128; w; w >>= 1) {
        if (t < w) red[t] = fmaxf(red[t], red[t + w]);
        __syncthreads();
    }
    float M = red[0]; __syncthreads();

    float s = 0.f;
    for (int c = t; c < NCH; c += 256) s += srow[c] * __expf(mrow[c] - M);
    red[t] = s; __syncthreads();
    for (int w = 128; w; w >>= 1) {
        if (t < w) red[t] += red[t + w];
        __syncthreads();
    }
    if (t == 0) {
        float lse = M + logf(red[0]);
        logp[id] = z[id] - lse;
    }
}

// ---------------------------------------------------------------------------
// Batch means + SPPO-hard loss. 1 block.
// ---------------------------------------------------------------------------
__global__ void final_loss(const float* __restrict__ logp,
                           const int* __restrict__ y,
                           float* __restrict__ out)
{
    __shared__ float lp[8];
    int t = threadIdx.x;
    if (t < 8) {
        int model = t >> 2, b = t & 3;
        float s = 0.f, cnt = 0.f;
        for (int i = 0; i < T; i++) {
            int tok = b * T + i;
            if (y[tok] != IGN) { s += logp[model * TOK + tok]; cnt += 1.f; }
        }
        lp[t] = s / cnt;
    }
    __syncthreads();
    if (t == 0) {
        float a0 = lp[0] - lp[4], a1 = lp[1] - lp[5];
        float b0 = lp[2] - lp[6], b1 = lp[3] - lp[7];
        float l0 = (a0 - 5.f) * (a0 - 5.f) + (b0 + 5.f) * (b0 + 5.f);
        float l1 = (a1 - 5.f) * (a1 - 5.f) + (b1 + 5.f) * (b1 + 5.f);
        out[0] = -(l0 + l1) * 0.5f;
    }
}

extern "C" void kernel_launch(void* const* d_in, const int* in_sizes, int n_in,
                              void* d_out, int out_size, void* d_ws, size_t ws_size,
                              hipStream_t stream)
{
    const float* X  = (const float*)d_in[0];
    const float* Xr = (const float*)d_in[1];
    const int*   y  = (const int*)d_in[2];
    const float* Wp = (const float*)d_in[3];
    const float* Wr = (const float*)d_in[4];
    float* out = (float*)d_out;

    // shared ws layout (floats first, then bf16 arrays for fast path)
    float* ws   = (float*)d_ws;
    const size_t msElems = (size_t)2 * TOK * NCH;   // 2,048,000
    float* ms_m = ws;
    float* ms_s = ws + msElems;
    float* z    = ws + 2 * msElems;
    float* logp = z + 2 * TOK;
    u16*   Xb   = (u16*)(logp + 2 * TOK);
    u16*   Wb   = Xb + (size_t)2 * 2048 * H;        // + 8,388,608 shorts

    const size_t NEED = 2 * msElems * 4 + 4 * 2 * TOK * 4
                      + (size_t)2 * 2048 * H * 2 + (size_t)2 * V * H * 2;

    if (ws_size >= NEED) {
        // fast path: pre-convert to bf16, then 256^2 8-phase GEMM
        f32_to_bf16<<<1024, 256, 0, stream>>>(X,  Xb,                 (2048 * H) / 4);
        f32_to_bf16<<<1024, 256, 0, stream>>>(Xr, Xb + 2048 * H,      (2048 * H) / 4);
        f32_to_bf16<<<4096, 256, 0, stream>>>(Wp, Wb,                 (V * H) / 4);
        f32_to_bf16<<<4096, 256, 0, stream>>>(Wr, Wb + (size_t)V * H, (V * H) / 4);

        dim3 gg(2000);                     // (8 tok) x (125 vocab) x 2 models
        gemm_bf16<<<gg, 512, 0, stream>>>(Xb, Wb, ms_m, ms_s);
    } else {
        // fallback: round-1 known-correct path
        dim3 g1(TOK / BM, V / BN, 2);      // (32, 500, 2)
        gemm_partial<<<g1, 256, 0, stream>>>(X, Xr, Wp, Wr, ms_m, ms_s);
    }

    label_logit<<<(2 * TOK) / 4, 256, 0, stream>>>(X, Xr, Wp, Wr, y, z);
    lse_logp<<<2 * TOK, 256, 0, stream>>>(ms_m, ms_s, z, logp);
    final_loss<<<1, 64, 0, stream>>>(logp, y, out);
}

// Round 2
// 1103.144 us; speedup vs baseline: 1.1773x; 1.0350x over previous
//
#include <hip/hip_runtime.h>
#include <hip/hip_bf16.h>
#include <math.h>

#define H 2048
#define V 32000
#define T 512
#define TOK 2048        // B*T tokens per model
#define IGN (-100)

// round-1 fallback tile
#define BM 64
#define BN 64
#define BK 32
#define NCH (V / BN)    // 500 chunks of 64 cols (shared by both paths)

typedef unsigned short u16;
typedef __attribute__((ext_vector_type(8))) short short8;
typedef __attribute__((ext_vector_type(4))) float f32x4;

__device__ __forceinline__ u16 f2bf(float f) {
    unsigned int u = __float_as_uint(f);
    u += 0x7fffu + ((u >> 16) & 1u);   // round-to-nearest-even
    return (u16)(u >> 16);
}

#define GLD16(gp, lp) __builtin_amdgcn_global_load_lds( \
    (const __attribute__((address_space(1))) unsigned int*)(gp), \
    (__attribute__((address_space(3))) unsigned int*)(lp), 16, 0, 0)

// ---------------------------------------------------------------------------
// Convert f32 -> bf16 (RNE), vectorized. n4 = element count / 4.
// ---------------------------------------------------------------------------
__global__ __launch_bounds__(256) void f32_to_bf16(
    const float* __restrict__ src, u16* __restrict__ dst, int n4)
{
    for (int i = blockIdx.x * 256 + threadIdx.x; i < n4; i += gridDim.x * 256) {
        float4 v = ((const float4*)src)[i];
        ushort4 o;
        o.x = f2bf(v.x); o.y = f2bf(v.y); o.z = f2bf(v.z); o.w = f2bf(v.w);
        ((ushort4*)dst)[i] = o;
    }
}

// ---------------------------------------------------------------------------
// 256x256 tile, BK=64, 8 waves as 4M x 2N (per-wave 64 rows x 128 cols).
// 8-phase schedule; every B (column-quadrant) ds_read is issued ONE PHASE
// BEFORE its consumer and drains under the previous MFMA cluster; the A
// bank (8 reads/K-tile) is reloaded at a phase END (drains across the
// barrier into the next section). Counted vmcnt only; counted lgkm(8) on
// read-ahead phases, free lgkm(0) elsewhere (preserves cross-wave
// stage/read safety: every read-site follows [all-waves vmcnt][barrier]).
// Stage slot map (half-tiles, per iter = tiles u(buf0), u+1(buf1)):
//   P0: u+1.B1->buf1  P1: u+1.A0->buf1  P2: u+1.A1->buf1  P3: u+2.B0->buf0
//   P4: u+2.B1->buf0  P5: u+2.A0->buf0  P6: u+2.A1->buf0  P7: u+3.B0->buf1
// Reads: P_i section: bfQ_{i+1 mod 4} (next buffer at wrap);
//        P3/P7 end:   af(next K-tile) after QUAD.
// vmcnt: P2/P6 end: vmcnt(4) (guards wrap bfQ0 read after barrier);
//        P3/P7 pre-barrier: vmcnt(2) (guards af read after barrier).
// Tail: stage addrs k-clamped to tile 31 (redundant loads, unconsumed reads).
// ---------------------------------------------------------------------------
__global__ __launch_bounds__(512, 2) void gemm_bf16(
    const u16* __restrict__ Xb, const u16* __restrict__ Wb,
    float* __restrict__ ms_m, float* __restrict__ ms_s)
{
    __shared__ __align__(16) u16 lds[65536];   // 128 KiB
    // shorts: buf b: A halves b*32768 + {0,8192}; B halves 16384+b*32768+{0,8192}

    const int tid  = threadIdx.x;
    const int wave = tid >> 6;
    const int lane = tid & 63;
    const int q    = lane >> 4;
    const int rl   = lane & 15;
    const int wm   = wave >> 1;      // 0..3  (M quarter: 64 rows)
    const int wn   = wave & 1;       // 0..1  (N half: 128 cols)
    const int ah   = wm >> 1;        // which A half-buffer
    const int am   = wm & 1;         // 64-row half within it

    // XCD-chunked bijective swizzle: 2000 wgs, 2000 % 8 == 0.
    const int lin = (int)blockIdx.x;
    const int wg  = (lin & 7) * 250 + (lin >> 3);
    const int bx  = wg & 7;          // 8 token tiles
    const int rem = wg >> 3;         // 0..249
    const int by  = rem % 125;       // 125 vocab tiles
    const int model = rem / 125;

    const size_t tokBase = (size_t)bx * 256;
    const size_t vBase   = (size_t)by * 256;

    const u16* __restrict__ A   = Xb + (size_t)model * (2048ULL * H) + tokBase * H;
    const u16* __restrict__ Bm  = Wb + (size_t)model * ((size_t)V * H) + vBase * H;
    const u16* __restrict__ A1p = A  + 128 * H;
    const u16* __restrict__ B1p = Bm + 128 * H;

    // Staging: half-tile = 128 rows x 64 k; linear LDS dest, XOR swizzle
    // realized on the global address (phys slot g holds logical g^(r&7)).
    const int G0 = wave * 64 + lane;
    const int G1 = G0 + 512;
    const int r0 = G0 >> 3, s0 = (G0 & 7) ^ (r0 & 7);
    const int r1 = G1 >> 3, s1 = (G1 & 7) ^ (r1 & 7);
    const int off0 = r0 * H + s0 * 8;
    const int off1 = r1 * H + s1 * 8;
    const int ldsS0 = wave * 512;
    const int ldsS1 = 4096 + wave * 512;

#define STAGE(gp, hb) do { \
    GLD16((gp) + off0, lds + (hb) + ldsS0); \
    GLD16((gp) + off1, lds + (hb) + ldsS1); \
} while (0)

    // Fragment offsets within a half-buffer (shorts); ks=1 flips slot bit2 (^32).
    const int sB = (q ^ (rl & 7)) << 3;
    int aoff[4], pb[2];
#pragma unroll
    for (int f = 0; f < 4; ++f) aoff[f] = (am * 64 + f * 16 + rl) * 64 + sB;
#pragma unroll
    for (int fn = 0; fn < 2; ++fn) pb[fn] = (fn * 16 + rl) * 64 + sB;

    short8 af[4][2];          // A bank: current K-tile, this wave's 64 rows
    short8 bf[2][2][2];       // [Q&1][fn][ks]  B quadrant ping-pong
    f32x4 acc[4][8];          // [rowfrag][Q*2+fn]
#pragma unroll
    for (int a = 0; a < 4; ++a)
#pragma unroll
        for (int b = 0; b < 8; ++b) acc[a][b] = (f32x4){0.f, 0.f, 0.f, 0.f};

#define LDA(buf) do { \
    _Pragma("unroll") \
    for (int f = 0; f < 4; ++f) { \
        const int o_ = (buf) * 32768 + ah * 8192 + aoff[f]; \
        af[f][0] = *(const short8*)(lds + o_); \
        af[f][1] = *(const short8*)(lds + (o_ ^ 32)); \
    } } while (0)

#define LDBQ(buf, Q) do { \
    _Pragma("unroll") \
    for (int fn = 0; fn < 2; ++fn) { \
        const int o_ = 16384 + (buf) * 32768 + wn * 8192 + (Q) * 2048 + pb[fn]; \
        bf[(Q) & 1][fn][0] = *(const short8*)(lds + o_); \
        bf[(Q) & 1][fn][1] = *(const short8*)(lds + (o_ ^ 32)); \
    } } while (0)

// ks-outer: 8 independent MFMAs, then their 8 dependents (breaks dep pairs).
#define QUAD(Q) do { \
    __builtin_amdgcn_s_setprio(1); \
    _Pragma("unroll") \
    for (int ks = 0; ks < 2; ++ks) \
    _Pragma("unroll") \
    for (int f = 0; f < 4; ++f) \
    _Pragma("unroll") \
    for (int fn = 0; fn < 2; ++fn) \
        acc[f][(Q) * 2 + fn] = __builtin_amdgcn_mfma_f32_16x16x32_bf16( \
            af[f][ks], bf[(Q) & 1][fn][ks], acc[f][(Q) * 2 + fn], 0, 0, 0); \
    __builtin_amdgcn_s_setprio(0); \
} while (0)

#define PREBAR()  do { __builtin_amdgcn_s_barrier(); asm volatile("" ::: "memory"); } while (0)
#define POST0()   do { asm volatile("s_waitcnt lgkmcnt(0)" ::: "memory"); \
                       __builtin_amdgcn_s_barrier(); asm volatile("" ::: "memory"); } while (0)
#define POST8()   do { asm volatile("s_waitcnt lgkmcnt(8)" ::: "memory"); \
                       __builtin_amdgcn_s_barrier(); asm volatile("" ::: "memory"); } while (0)
#define VMCNT(n)  asm volatile("s_waitcnt vmcnt(" #n ")" ::: "memory")

    // Prologue: t0 {B0,B1,A0,A1}->buf0, t1.B0->buf1 (10 loads); wait t0; read
    // af(t0) + bfQ0(t0).
    STAGE(Bm,       16384); STAGE(B1p,      24576);
    STAGE(A,            0); STAGE(A1p,       8192);
    STAGE(Bm + 64,  49152);
    VMCNT(2);
    __builtin_amdgcn_s_barrier();
    asm volatile("" ::: "memory");
    LDA(0);
    LDBQ(0, 0);

#pragma unroll 1
    for (int i = 0; i < 16; ++i) {          // tiles u=2i (buf0), u+1 (buf1)
        const int u  = 2 * i;
        const int k1 = (u + 1) * 64;
        const int k2 = (u + 2 < 32 ? u + 2 : 31) * 64;   // tail clamp
        const int k3 = (u + 3 < 32 ? u + 3 : 31) * 64;
        // P0
        LDBQ(0, 1);
        STAGE(B1p + k1, 57344);
        PREBAR(); QUAD(0); POST0();
        // P1
        LDBQ(0, 2);
        STAGE(A + k1, 32768);
        PREBAR(); QUAD(1); POST0();
        // P2
        LDBQ(0, 3);
        STAGE(A1p + k1, 40960);
        PREBAR(); QUAD(2);
        VMCNT(4); POST0();
        // P3
        LDBQ(1, 0);
        STAGE(Bm + k2, 16384);
        VMCNT(2); PREBAR();
        QUAD(3);
        LDA(1);                              // af(u+1) from buf1; drains onward
        POST8();
        // P4
        LDBQ(1, 1);
        STAGE(B1p + k2, 24576);
        PREBAR(); QUAD(0); POST0();
        // P5
        LDBQ(1, 2);
        STAGE(A + k2, 0);
        PREBAR(); QUAD(1); POST0();
        // P6
        LDBQ(1, 3);
        STAGE(A1p + k2, 8192);
        PREBAR(); QUAD(2);
        VMCNT(4); POST0();
        // P7
        LDBQ(0, 0);
        STAGE(Bm + k3, 49152);
        VMCNT(2); PREBAR();
        QUAD(3);
        LDA(0);                              // af(u+2) from buf0
        POST8();
    }

    // Epilogue: per-row partial (max, sumexp) over two 64-col chunks.
    // Row = wm*64 + f*16 + q*4 + i ; cols = wn*128 + [0,64) / [64,128).
    const int cA = by * 4 + wn * 2;
    const size_t rowB = (size_t)model * TOK + tokBase + (size_t)wm * 64;
#pragma unroll
    for (int f = 0; f < 4; ++f) {
#pragma unroll
        for (int i2 = 0; i2 < 4; ++i2) {
            float a0 = acc[f][0][i2], a1 = acc[f][1][i2];
            float a2 = acc[f][2][i2], a3 = acc[f][3][i2];
            float mA = fmaxf(fmaxf(a0, a1), fmaxf(a2, a3));
#pragma unroll
            for (int off = 1; off < 16; off <<= 1)
                mA = fmaxf(mA, __shfl_xor(mA, off));
            float sA = __expf(a0 - mA) + __expf(a1 - mA)
                     + __expf(a2 - mA) + __expf(a3 - mA);
#pragma unroll
            for (int off = 1; off < 16; off <<= 1)
                sA += __shfl_xor(sA, off);

            float b0 = acc[f][4][i2], b1 = acc[f][5][i2];
            float b2 = acc[f][6][i2], b3 = acc[f][7][i2];
            float mB = fmaxf(fmaxf(b0, b1), fmaxf(b2, b3));
#pragma unroll
            for (int off = 1; off < 16; off <<= 1)
                mB = fmaxf(mB, __shfl_xor(mB, off));
            float sB2 = __expf(b0 - mB) + __expf(b1 - mB)
                      + __expf(b2 - mB) + __expf(b3 - mB);
#pragma unroll
            for (int off = 1; off < 16; off <<= 1)
                sB2 += __shfl_xor(sB2, off);

            if (rl == 0) {
                size_t idx = (rowB + f * 16 + q * 4 + i2) * NCH + cA;
                ms_m[idx]     = mA;
                ms_s[idx]     = sA;
                ms_m[idx + 1] = mB;
                ms_s[idx + 1] = sB2;
            }
        }
    }
#undef STAGE
#undef LDA
#undef LDBQ
#undef QUAD
#undef PREBAR
#undef POST0
#undef POST8
#undef VMCNT
}

// ---------------------------------------------------------------------------
// Round-1 fallback GEMM (known correct) — used only if ws too small.
// ---------------------------------------------------------------------------
__global__ __launch_bounds__(256) void gemm_partial(
    const float* __restrict__ X,  const float* __restrict__ Xr,
    const float* __restrict__ Wp, const float* __restrict__ Wr,
    float* __restrict__ ms_m, float* __restrict__ ms_s)
{
    __shared__ float smemF[64 * 65];
    short* smemS = (short*)smemF;
    short* ldsA = smemS;
    short* ldsB = smemS + 64 * 40;

    const int tid     = threadIdx.x;
    const int model   = blockIdx.z;
    const int tokBase = blockIdx.x * BM;
    const int vBase   = blockIdx.y * BN;

    const float* __restrict__ Xp = model ? Xr : X;
    const float* __restrict__ Wm = model ? Wr : Wp;

    const int lane = tid & 63;
    const int wave = tid >> 6;
    const int q    = lane >> 4;
    const int rl   = lane & 15;
    const int m0   = (wave >> 1) * 32;
    const int n0   = (wave & 1) * 32;

    f32x4 acc[2][2];
    for (int a = 0; a < 2; a++)
        for (int b = 0; b < 2; b++)
            acc[a][b] = (f32x4){0.f, 0.f, 0.f, 0.f};

    for (int kk = 0; kk < H / BK; kk++) {
        const int k0 = kk * BK;
        __syncthreads();
        for (int rep = 0; rep < 2; rep++) {
            int i   = tid + rep * 256;
            int row = i >> 3;
            int cf  = (i & 7) * 4;
            const float4 va = *(const float4*)(Xp + (size_t)(tokBase + row) * H + k0 + cf);
            short* pa = ldsA + row * 40 + cf;
            pa[0] = (short)f2bf(va.x); pa[1] = (short)f2bf(va.y);
            pa[2] = (short)f2bf(va.z); pa[3] = (short)f2bf(va.w);
            const float4 vb = *(const float4*)(Wm + (size_t)(vBase + row) * H + k0 + cf);
            short* pb = ldsB + row * 40 + cf;
            pb[0] = (short)f2bf(vb.x); pb[1] = (short)f2bf(vb.y);
            pb[2] = (short)f2bf(vb.z); pb[3] = (short)f2bf(vb.w);
        }
        __syncthreads();

        short8 aF[2], bF[2];
        for (int im = 0; im < 2; im++)
            aF[im] = *(const short8*)(ldsA + (m0 + im * 16 + rl) * 40 + q * 8);
        for (int in = 0; in < 2; in++)
            bF[in] = *(const short8*)(ldsB + (n0 + in * 16 + rl) * 40 + q * 8);

        for (int im = 0; im < 2; im++)
            for (int in = 0; in < 2; in++)
                acc[im][in] = __builtin_amdgcn_mfma_f32_16x16x32_bf16(
                    aF[im], bF[in], acc[im][in], 0, 0, 0);
    }

    __syncthreads();
    for (int im = 0; im < 2; im++)
        for (int in = 0; in < 2; in++)
            for (int i = 0; i < 4; i++)
                smemF[(m0 + im * 16 + q * 4 + i) * 65 + (n0 + in * 16 + rl)] =
                    acc[im][in][i];
    __syncthreads();

    if (tid < 64) {
        const float* rowp = smemF + tid * 65;
        float m = -INFINITY;
        for (int j = 0; j < 64; j++) m = fmaxf(m, rowp[j]);
        float s = 0.f;
        for (int j = 0; j < 64; j++) s += __expf(rowp[j] - m);
        size_t idx = ((size_t)model * TOK + (tokBase + tid)) * NCH + blockIdx.y;
        ms_m[idx] = m;
        ms_s[idx] = s;
    }
}

// ---------------------------------------------------------------------------
// Label logit per (model, token). One wave per token.
// ---------------------------------------------------------------------------
__global__ __launch_bounds__(256) void label_logit(
    const float* __restrict__ X,  const float* __restrict__ Xr,
    const float* __restrict__ Wp, const float* __restrict__ Wr,
    const int* __restrict__ y, float* __restrict__ z)
{
    int id    = blockIdx.x * 4 + (threadIdx.x >> 6);  // 0..4095
    int lane  = threadIdx.x & 63;
    int model = id >> 11;
    int token = id & 2047;
    const float* __restrict__ Xp = model ? Xr : X;
    const float* __restrict__ Wm = model ? Wr : Wp;
    int lab = y[token];
    float sum = 0.f;
    if (lab != IGN) {
        const float* xp = Xp + (size_t)token * H;
        const float* wp = Wm + (size_t)lab * H;
        for (int c = lane; c < H; c += 64) sum += xp[c] * wp[c];
    }
    for (int off = 32; off; off >>= 1) sum += __shfl_down(sum, off);
    if (lane == 0) z[id] = sum;
}

// ---------------------------------------------------------------------------
// Combine 500 partial (m,s) per (model,token) -> logp.
// ---------------------------------------------------------------------------
__global__ __launch_bounds__(256) void lse_logp(
    const float* __restrict__ ms_m, const float* __restrict__ ms_s,
    const float* __restrict__ z, float* __restrict__ logp)
{
    int id = blockIdx.x;   // 0..4095
    int t  = threadIdx.x;
    __shared__ float red[256];
    const float* mrow = ms_m + (size_t)id * NCH;
    const float* srow = ms_s + (size_t)id * NCH;

    float m = -INFINITY;
    for (int c = t; c < NCH; c += 256) m = fmaxf(m, mrow[c]);
    red[t] = m; __syncthreads();
    for (int w = 128; w; w >>= 1) {
        if (t < w) red[t] = fmaxf(red[t], red[t + w]);
        __syncthreads();
    }
    float M = red[0]; __syncthreads();

    float s = 0.f;
    for (int c = t; c < NCH; c += 256) s += srow[c] * __expf(mrow[c] - M);
    red[t] = s; __syncthreads();
    for (int w = 128; w; w >>= 1) {
        if (t < w) red[t] += red[t + w];
        __syncthreads();
    }
    if (t == 0) {
        float lse = M + logf(red[0]);
        logp[id] = z[id] - lse;
    }
}

// ---------------------------------------------------------------------------
// Batch means + SPPO-hard loss. 1 block.
// ---------------------------------------------------------------------------
__global__ void final_loss(const float* __restrict__ logp,
                           const int* __restrict__ y,
                           float* __restrict__ out)
{
    __shared__ float lp[8];
    int t = threadIdx.x;
    if (t < 8) {
        int model = t >> 2, b = t & 3;
        float s = 0.f, cnt = 0.f;
        for (int i = 0; i < T; i++) {
            int tok = b * T + i;
            if (y[tok] != IGN) { s += logp[model * TOK + tok]; cnt += 1.f; }
        }
        lp[t] = s / cnt;
    }
    __syncthreads();
    if (t == 0) {
        float a0 = lp[0] - lp[4], a1 = lp[1] - lp[5];
        float b0 = lp[2] - lp[6], b1 = lp[3] - lp[7];
        float l0 = (a0 - 5.f) * (a0 - 5.f) + (b0 + 5.f) * (b0 + 5.f);
        float l1 = (a1 - 5.f) * (a1 - 5.f) + (b1 + 5.f) * (b1 + 5.f);
        out[0] = -(l0 + l1) * 0.5f;
    }
}

extern "C" void kernel_launch(void* const* d_in, const int* in_sizes, int n_in,
                              void* d_out, int out_size, void* d_ws, size_t ws_size,
                              hipStream_t stream)
{
    const float* X  = (const float*)d_in[0];
    const float* Xr = (const float*)d_in[1];
    const int*   y  = (const int*)d_in[2];
    const float* Wp = (const float*)d_in[3];
    const float* Wr = (const float*)d_in[4];
    float* out = (float*)d_out;

    // shared ws layout (floats first, then bf16 arrays for fast path)
    float* ws   = (float*)d_ws;
    const size_t msElems = (size_t)2 * TOK * NCH;   // 2,048,000
    float* ms_m = ws;
    float* ms_s = ws + msElems;
    float* z    = ws + 2 * msElems;
    float* logp = z + 2 * TOK;
    u16*   Xb   = (u16*)(logp + 2 * TOK);
    u16*   Wb   = Xb + (size_t)2 * 2048 * H;        // + 8,388,608 shorts

    const size_t NEED = 2 * msElems * 4 + 4 * 2 * TOK * 4
                      + (size_t)2 * 2048 * H * 2 + (size_t)2 * V * H * 2;

    if (ws_size >= NEED) {
        // fast path: pre-convert to bf16, then 256^2 8-phase GEMM
        f32_to_bf16<<<1024, 256, 0, stream>>>(X,  Xb,                 (2048 * H) / 4);
        f32_to_bf16<<<1024, 256, 0, stream>>>(Xr, Xb + 2048 * H,      (2048 * H) / 4);
        f32_to_bf16<<<4096, 256, 0, stream>>>(Wp, Wb,                 (V * H) / 4);
        f32_to_bf16<<<4096, 256, 0, stream>>>(Wr, Wb + (size_t)V * H, (V * H) / 4);

        dim3 gg(2000);                     // (8 tok) x (125 vocab) x 2 models
        gemm_bf16<<<gg, 512, 0, stream>>>(Xb, Wb, ms_m, ms_s);
    } else {
        // fallback: round-1 known-correct path
        dim3 g1(TOK / BM, V / BN, 2);      // (32, 500, 2)
        gemm_partial<<<g1, 256, 0, stream>>>(X, Xr, Wp, Wr, ms_m, ms_s);
    }

    label_logit<<<(2 * TOK) / 4, 256, 0, stream>>>(X, Xr, Wp, Wr, y, z);
    lse_logp<<<2 * TOK, 256, 0, stream>>>(ms_m, ms_s, z, logp);
    final_loss<<<1, 64, 0, stream>>>(logp, y, out);
}